// Round 9
// baseline (1374.262 us; speedup 1.0000x reference)
//
#include <hip/hip_runtime.h>
#include <hip/hip_bf16.h>

#define B_ 64
#define S_ 2048
#define T_ 256

typedef _Float16 half2_t __attribute__((ext_vector_type(2)));

__device__ __forceinline__ float fdot2f(half2_t a, half2_t b, float c) {
  return __builtin_amdgcn_fdot2(a, b, c, false);
}
__device__ __forceinline__ half2_t pack2(float a, float b) {
  return __builtin_bit_cast(half2_t, __builtin_amdgcn_cvt_pkrtz(a, b));
}
template <int CTRL>
__device__ __forceinline__ float dpp_max(float v) {
  const int t = __builtin_amdgcn_update_dpp(0, __builtin_bit_cast(int, v), CTRL, 0xF, 0xF, true);
  return fmaxf(v, __builtin_bit_cast(float, t));
}
template <int CTRL>
__device__ __forceinline__ float dpp_add(float v) {
  const int t = __builtin_amdgcn_update_dpp(0, __builtin_bit_cast(int, v), CTRL, 0xF, 0xF, true);
  return v + __builtin_bit_cast(float, t);
}

// lgkm-only barrier: LDS visibility without draining in-flight global prefetch
__device__ __forceinline__ void wg_barrier() {
  __builtin_amdgcn_sched_barrier(0);
  asm volatile("s_waitcnt lgkmcnt(0)" ::: "memory");
  __builtin_amdgcn_s_barrier();
  asm volatile("" ::: "memory");
  __builtin_amdgcn_sched_barrier(0);
}

// ---------------- numerator score: ws[b] ----------------
__global__ void crf_score(const float* __restrict__ em, const int* __restrict__ tags,
                          const int* __restrict__ mask, const float* __restrict__ trans,
                          const float* __restrict__ startt, const float* __restrict__ endt,
                          float* __restrict__ ws) {
  const int b = blockIdx.x;
  const int t = threadIdx.x;  // 256
  const int* tg = tags + b * S_;
  const int* mk = mask + b * S_;
  const float* eb = em + (size_t)b * S_ * T_;

  float sc = 0.f;
  int msum = 0;
  for (int s = t; s < S_; s += 256) {
    const int tag = tg[s];
    const int m = mk[s];
    msum += m;
    const float e = eb[(size_t)s * T_ + tag];
    if (s == 0) {
      sc += startt[tag] + e;
    } else {
      const int pt = tg[s - 1];
      sc += (trans[tag * T_ + pt] + e) * (float)m;
    }
  }
#pragma unroll
  for (int off = 32; off > 0; off >>= 1) {
    sc += __shfl_down(sc, off);
    msum += __shfl_down(msum, off);
  }
  __shared__ float ssc[4];
  __shared__ int smc[4];
  const int wv = t >> 6, ln = t & 63;
  if (ln == 0) { ssc[wv] = sc; smc[wv] = msum; }
  __syncthreads();
  if (t == 0) {
    const float s4 = (ssc[0] + ssc[1]) + (ssc[2] + ssc[3]);
    const int m4 = smc[0] + smc[1] + smc[2] + smc[3];
    const int last = tg[m4 - 1];
    ws[b] = s4 + endt[last];
  }
}

// ---------------- forward algorithm (log Z): ws[64+b] ----------------
// Radix-2 step pairing: per barrier-pair, compute step s1 (j-split, full-i) AND the
// i-quarter partials of step s2 (no barrier between: own-quarter x exchanged via
// intra-wave LDS write -> lgkmcnt(0) -> read). Barrier B1, assemble s2 from 4 partials
// (+E, exact pow2 renorm), scatter-write alpha, barrier B2. Two barriers per TWO steps.
// W held twice in VGPRs: w2 = 32i x 8j column slice (dot1), wp = 64i x 4j row slice
// (pdot). Renorm: exact 1-stale pow2 from POST-E stored-x max (r6/r8 stable scheme).
__global__ __launch_bounds__(256, 1) void crf_forward(
    const float* __restrict__ em, const float* __restrict__ trans,
    const float* __restrict__ startt, const float* __restrict__ endt,
    float* __restrict__ ws) {
  const int b = blockIdx.x;
  const int tid = threadIdx.x;  // 0..255
  const int jgG = tid >> 3;     // 0..31  (dot1: j = 8jgG + h)
  const int ig = tid & 7;       // 0..7   (dot1: i in [32ig, 32ig+32))
  const int w = tid >> 6;       // wave 0..3
  const int lane = tid & 63;
  const int jown = (w << 6) + lane;  // seg2-owned output column
  const float* eb = em + (size_t)b * S_ * T_;

  __shared__ __align__(16) unsigned char aA[512];   // alpha f16, rotated 16B units
  __shared__ __align__(16) unsigned char aB[512];   // per-wave quarter scratch (linear)
  __shared__ __align__(16) float pbuf[4][T_];       // i-quarter partials (f32)
  __shared__ __align__(16) float ebuf[2][8][T_];    // staged exp(emissions)
  __shared__ float mpA[16];                         // 16-lane-group maxes of stored x
  __shared__ float mpB[16];                         // same, for mid-pair x_s1
  __shared__ float fsum[4];

  // --- W column slice (dot1): w2[q][h] = (W[32ig+2q][8jgG+h], W[32ig+2q+1][...])
  half2_t w2[16][8];
#pragma unroll
  for (int q = 0; q < 16; ++q) {
    const int i0 = 32 * ig + 2 * q;
#pragma unroll
    for (int h = 0; h < 8; ++h) {
      const int j = 8 * jgG + h;
      w2[q][h] = pack2(__expf(trans[i0 * T_ + j]), __expf(trans[(i0 + 1) * T_ + j]));
    }
  }
  // --- W row slice (pdot): wp[q][c] = (W[64w+2q][4*lane+c], W[64w+2q+1][4*lane+c])
  half2_t wp[32][4];
#pragma unroll
  for (int q = 0; q < 32; ++q) {
    const int i0 = 64 * w + 2 * q;
#pragma unroll
    for (int c = 0; c < 4; ++c) {
      const int j = 4 * lane + c;
      wp[q][c] = pack2(__expf(trans[i0 * T_ + j]), __expf(trans[(i0 + 1) * T_ + j]));
    }
  }

  // aA reader offsets (rotated): logical unit r of block ig at phys 4ig + ((r+ig)&3)
  int roff[4];
#pragma unroll
  for (int r = 0; r < 4; ++r) roff[r] = (4 * ig + ((r + ig) & 3)) * 16;
  // aA writer byte for jown (b16 scatter, same rotation)
  const int wblk = jown >> 5;
  const int wbyteA = wblk * 64 + (((jown >> 3) & 3) + wblk & 3) * 16 + (jown & 7) * 2;
  // aB: wave quarter base; seg1 writer (ig==0) unit = jg-in-wave
  unsigned char* aBq = aB + w * 128;
  const int aBw = ((lane >> 3)) * 16;

  // --- init: al0 = start + em[0], j = tid (1/lane), exact global max m0
  const float al0 = startt[tid] + eb[tid];
  float lm = al0;
  lm = dpp_max<0xB1>(lm);
  lm = dpp_max<0x4E>(lm);
  lm = dpp_max<0x141>(lm);
  lm = dpp_max<0x140>(lm);
  lm = fmaxf(lm, __shfl_xor(lm, 16));
  lm = fmaxf(lm, __shfl_xor(lm, 32));
  if (lane == 0) fsum[w] = lm;
  __syncthreads();
  const float m0 = fmaxf(fmaxf(fsum[0], fsum[1]), fmaxf(fsum[2], fsum[3]));
  {
    const float x0 = __expf(al0 - m0);
    // scatter b16 into rotated aA at this lane's jown... (init j == tid)
    const int blk0 = tid >> 5;
    const int by0 = blk0 * 64 + ((((tid >> 3) & 3) + blk0) & 3) * 16 + (tid & 7) * 2;
    *(_Float16*)(aA + by0) = (_Float16)x0;
    float gx = x0;
    gx = dpp_max<0xB1>(gx);
    gx = dpp_max<0x4E>(gx);
    gx = dpp_max<0x141>(gx);
    gx = dpp_max<0x140>(gx);
    if ((tid & 15) == 0) mpA[tid >> 4] = gx;
  }
  // stage chunk 0 (rows 1..8): wave w does rows {2w+1, 2w+2}
  const int col = lane * 4;
  {
    float4 f0 = *(const float4*)(eb + (size_t)(1 + 2 * w) * T_ + col);
    float4 f1 = *(const float4*)(eb + (size_t)(2 + 2 * w) * T_ + col);
    f0.x = __expf(f0.x); f0.y = __expf(f0.y); f0.z = __expf(f0.z); f0.w = __expf(f0.w);
    f1.x = __expf(f1.x); f1.y = __expf(f1.y); f1.z = __expf(f1.z); f1.w = __expf(f1.w);
    *(float4*)&ebuf[0][2 * w][col] = f0;
    *(float4*)&ebuf[0][2 * w + 1][col] = f1;
  }
  __syncthreads();
  float4 pre0 = *(const float4*)(eb + (size_t)(9 + 2 * w) * T_ + col);
  float4 pre1 = *(const float4*)(eb + (size_t)(10 + 2 * w) * T_ + col);

  int cur = 0;
  int k_run = 0;
  float xf[8];

  // helper lambda-ish macro for 16-value max combine from a 16-float LDS buffer
#define COMBINE16(dst, buf)                                                       \
  {                                                                               \
    const float4 a0 = *(const float4*)&buf[0];                                    \
    const float4 a1 = *(const float4*)&buf[4];                                    \
    const float4 a2 = *(const float4*)&buf[8];                                    \
    const float4 a3 = *(const float4*)&buf[12];                                   \
    dst = fmaxf(fmaxf(fmaxf(a0.x, a0.y), fmaxf(a0.z, a0.w)),                      \
                fmaxf(fmaxf(fmaxf(a1.x, a1.y), fmaxf(a1.z, a1.w)),                \
                      fmaxf(fmaxf(fmaxf(a2.x, a2.y), fmaxf(a2.z, a2.w)),          \
                            fmaxf(fmaxf(a3.x, a3.y), fmaxf(a3.z, a3.w)))));       \
  }

  for (int p = 0; p < (S_ - 2) / 2; ++p) {
    const int s2 = 2 * p + 2;
    const int sc1 = (2 * p) & 7;
    const int sc2 = (2 * p + 1) & 7;
    // ---- rsA from stored-x maxes (off critical path)
    float mhA;
    COMBINE16(mhA, mpA);
    int ueA = (int)(__builtin_bit_cast(unsigned, mhA) >> 23) - 127;
    ueA = (ueA < -20) ? -20 : ueA;
    const float rsA = __builtin_bit_cast(float, (unsigned)((119 - ueA) << 23));

    // ---- dot1: acc[h] = sum_{i in block ig} x[i] * W[i][8jgG+h]
    const float4 blk0 = *(const float4*)(aA + roff[0]);
    const float4 blk1 = *(const float4*)(aA + roff[1]);
    const float4 blk2 = *(const float4*)(aA + roff[2]);
    const float4 blk3 = *(const float4*)(aA + roff[3]);
    float acc[8] = {0.f, 0.f, 0.f, 0.f, 0.f, 0.f, 0.f, 0.f};
    const float4 blks[4] = {blk0, blk1, blk2, blk3};
#pragma unroll
    for (int r = 0; r < 4; ++r) {
      const half2_t a0 = __builtin_bit_cast(half2_t, blks[r].x);
      const half2_t a1 = __builtin_bit_cast(half2_t, blks[r].y);
      const half2_t a2 = __builtin_bit_cast(half2_t, blks[r].z);
      const half2_t a3 = __builtin_bit_cast(half2_t, blks[r].w);
#pragma unroll
      for (int h = 0; h < 8; ++h) {
        acc[h] = fdot2f(a0, w2[4 * r + 0][h], acc[h]);
        acc[h] = fdot2f(a1, w2[4 * r + 1][h], acc[h]);
        acc[h] = fdot2f(a2, w2[4 * r + 2][h], acc[h]);
        acc[h] = fdot2f(a3, w2[4 * r + 3][h], acc[h]);
      }
    }
#pragma unroll
    for (int h = 0; h < 8; ++h) {
      acc[h] = dpp_add<0xB1>(acc[h]);
      acc[h] = dpp_add<0x4E>(acc[h]);
      acc[h] = dpp_add<0x141>(acc[h]);
    }
    // ---- x_s1 = acc * rsA * E1  (all lanes; post-E max -> stable renorm)
    const float4 E0 = *(const float4*)&ebuf[cur][sc1][8 * jgG];
    const float4 E1 = *(const float4*)&ebuf[cur][sc1][8 * jgG + 4];
    xf[0] = acc[0] * (rsA * E0.x); xf[1] = acc[1] * (rsA * E0.y);
    xf[2] = acc[2] * (rsA * E0.z); xf[3] = acc[3] * (rsA * E0.w);
    xf[4] = acc[4] * (rsA * E1.x); xf[5] = acc[5] * (rsA * E1.y);
    xf[6] = acc[6] * (rsA * E1.z); xf[7] = acc[7] * (rsA * E1.w);
    float mxB = fmaxf(fmaxf(fmaxf(xf[0], xf[1]), fmaxf(xf[2], xf[3])),
                      fmaxf(fmaxf(xf[4], xf[5]), fmaxf(xf[6], xf[7])));
    mxB = dpp_max<0x140>(mxB);
    if ((lane & 15) == 0) mpB[tid >> 4] = mxB;
    if (ig == 0) {
      union { half2_t h[4]; float4 f; } uu;
      uu.h[0] = pack2(xf[0], xf[1]); uu.h[1] = pack2(xf[2], xf[3]);
      uu.h[2] = pack2(xf[4], xf[5]); uu.h[3] = pack2(xf[6], xf[7]);
      *(float4*)(aBq + aBw) = uu.f;
    }
    // ---- intra-wave exchange: own-quarter visible to own wave (no barrier)
    asm volatile("s_waitcnt lgkmcnt(0)" ::: "memory");
    // ---- pdot: pc[c] = sum_{i in Q_w} x_s1[i] * W[i][4*lane+c]   (uniform reads)
    const float4 u0 = *(const float4*)(aBq + 0);
    const float4 u1 = *(const float4*)(aBq + 16);
    const float4 u2 = *(const float4*)(aBq + 32);
    const float4 u3 = *(const float4*)(aBq + 48);
    const float4 u4 = *(const float4*)(aBq + 64);
    const float4 u5 = *(const float4*)(aBq + 80);
    const float4 u6 = *(const float4*)(aBq + 96);
    const float4 u7 = *(const float4*)(aBq + 112);
    float pc0 = 0.f, pc1 = 0.f, pc2 = 0.f, pc3 = 0.f;
    const float4 us[8] = {u0, u1, u2, u3, u4, u5, u6, u7};
#pragma unroll
    for (int u = 0; u < 8; ++u) {
      const half2_t v0 = __builtin_bit_cast(half2_t, us[u].x);
      const half2_t v1 = __builtin_bit_cast(half2_t, us[u].y);
      const half2_t v2 = __builtin_bit_cast(half2_t, us[u].z);
      const half2_t v3 = __builtin_bit_cast(half2_t, us[u].w);
      pc0 = fdot2f(v0, wp[4 * u + 0][0], pc0);
      pc1 = fdot2f(v0, wp[4 * u + 0][1], pc1);
      pc2 = fdot2f(v0, wp[4 * u + 0][2], pc2);
      pc3 = fdot2f(v0, wp[4 * u + 0][3], pc3);
      pc0 = fdot2f(v1, wp[4 * u + 1][0], pc0);
      pc1 = fdot2f(v1, wp[4 * u + 1][1], pc1);
      pc2 = fdot2f(v1, wp[4 * u + 1][2], pc2);
      pc3 = fdot2f(v1, wp[4 * u + 1][3], pc3);
      pc0 = fdot2f(v2, wp[4 * u + 2][0], pc0);
      pc1 = fdot2f(v2, wp[4 * u + 2][1], pc1);
      pc2 = fdot2f(v2, wp[4 * u + 2][2], pc2);
      pc3 = fdot2f(v2, wp[4 * u + 2][3], pc3);
      pc0 = fdot2f(v3, wp[4 * u + 3][0], pc0);
      pc1 = fdot2f(v3, wp[4 * u + 3][1], pc1);
      pc2 = fdot2f(v3, wp[4 * u + 3][2], pc2);
      pc3 = fdot2f(v3, wp[4 * u + 3][3], pc3);
    }
    {
      float4 pv; pv.x = pc0; pv.y = pc1; pv.z = pc2; pv.w = pc3;
      *(float4*)&pbuf[w][4 * lane] = pv;
    }
    k_run += ueA + 8;
    wg_barrier();  // B1

    // ---- seg2: assemble z_s2[jown] from 4 partials; renorm with rsB; store alpha
    float mhB;
    COMBINE16(mhB, mpB);
    int ueB = (int)(__builtin_bit_cast(unsigned, mhB) >> 23) - 127;
    ueB = (ueB < -20) ? -20 : ueB;
    const float rsB = __builtin_bit_cast(float, (unsigned)((119 - ueB) << 23));
    const float z2 = (pbuf[0][jown] + pbuf[1][jown]) + (pbuf[2][jown] + pbuf[3][jown]);
    const float E2 = ebuf[cur][sc2][jown];
    const float xn = z2 * (rsB * E2);
    *(_Float16*)(aA + wbyteA) = (_Float16)xn;
    float gx = xn;
    gx = dpp_max<0xB1>(gx);
    gx = dpp_max<0x4E>(gx);
    gx = dpp_max<0x141>(gx);
    gx = dpp_max<0x140>(gx);
    if ((tid & 15) == 0) mpA[tid >> 4] = gx;
    k_run += ueB + 8;
    // ---- chunk staging every 4 pairs (8 steps)
    if (sc2 == 7) {
      const int nxt = cur ^ 1;
      float4 f0 = pre0, f1 = pre1;
      f0.x = __expf(f0.x); f0.y = __expf(f0.y); f0.z = __expf(f0.z); f0.w = __expf(f0.w);
      f1.x = __expf(f1.x); f1.y = __expf(f1.y); f1.z = __expf(f1.z); f1.w = __expf(f1.w);
      *(float4*)&ebuf[nxt][2 * w][col] = f0;
      *(float4*)&ebuf[nxt][2 * w + 1][col] = f1;
      const int ck2 = ((s2 - 1) >> 3) + 2;
      if (ck2 < S_ / 8) {
        int row0 = 1 + ck2 * 8 + 2 * w;
        int row1 = row0 + 1;
        if (row0 > S_ - 1) row0 = S_ - 1;
        if (row1 > S_ - 1) row1 = S_ - 1;
        pre0 = *(const float4*)(eb + (size_t)row0 * T_ + col);
        pre1 = *(const float4*)(eb + (size_t)row1 * T_ + col);
      }
      cur = nxt;
    }
    wg_barrier();  // B2
  }

  // ---- tail step s = 2047 (sc = 6), then epilogue
  {
    float mhA;
    COMBINE16(mhA, mpA);
    int ueA = (int)(__builtin_bit_cast(unsigned, mhA) >> 23) - 127;
    ueA = (ueA < -20) ? -20 : ueA;
    const float rsA = __builtin_bit_cast(float, (unsigned)((119 - ueA) << 23));
    const float4 blk0 = *(const float4*)(aA + roff[0]);
    const float4 blk1 = *(const float4*)(aA + roff[1]);
    const float4 blk2 = *(const float4*)(aA + roff[2]);
    const float4 blk3 = *(const float4*)(aA + roff[3]);
    float acc[8] = {0.f, 0.f, 0.f, 0.f, 0.f, 0.f, 0.f, 0.f};
    const float4 blks[4] = {blk0, blk1, blk2, blk3};
#pragma unroll
    for (int r = 0; r < 4; ++r) {
      const half2_t a0 = __builtin_bit_cast(half2_t, blks[r].x);
      const half2_t a1 = __builtin_bit_cast(half2_t, blks[r].y);
      const half2_t a2 = __builtin_bit_cast(half2_t, blks[r].z);
      const half2_t a3 = __builtin_bit_cast(half2_t, blks[r].w);
#pragma unroll
      for (int h = 0; h < 8; ++h) {
        acc[h] = fdot2f(a0, w2[4 * r + 0][h], acc[h]);
        acc[h] = fdot2f(a1, w2[4 * r + 1][h], acc[h]);
        acc[h] = fdot2f(a2, w2[4 * r + 2][h], acc[h]);
        acc[h] = fdot2f(a3, w2[4 * r + 3][h], acc[h]);
      }
    }
#pragma unroll
    for (int h = 0; h < 8; ++h) {
      acc[h] = dpp_add<0xB1>(acc[h]);
      acc[h] = dpp_add<0x4E>(acc[h]);
      acc[h] = dpp_add<0x141>(acc[h]);
    }
    const int sct = (S_ - 2) & 7;  // = 6
    const float4 E0 = *(const float4*)&ebuf[cur][sct][8 * jgG];
    const float4 E1 = *(const float4*)&ebuf[cur][sct][8 * jgG + 4];
    xf[0] = acc[0] * (rsA * E0.x); xf[1] = acc[1] * (rsA * E0.y);
    xf[2] = acc[2] * (rsA * E0.z); xf[3] = acc[3] * (rsA * E0.w);
    xf[4] = acc[4] * (rsA * E1.x); xf[5] = acc[5] * (rsA * E1.y);
    xf[6] = acc[6] * (rsA * E1.z); xf[7] = acc[7] * (rsA * E1.w);
    k_run += ueA + 8;
  }
  float fin = 0.f;
  if (ig == 0) {
    const float4 en0 = *(const float4*)(endt + 8 * jgG);
    const float4 en1 = *(const float4*)(endt + 8 * jgG + 4);
    fin = xf[0] * __expf(en0.x) + xf[1] * __expf(en0.y) +
          xf[2] * __expf(en0.z) + xf[3] * __expf(en0.w) +
          xf[4] * __expf(en1.x) + xf[5] * __expf(en1.y) +
          xf[6] * __expf(en1.z) + xf[7] * __expf(en1.w);
  }
  fin = dpp_add<0xB1>(fin);
  fin = dpp_add<0x4E>(fin);
  fin = dpp_add<0x141>(fin);
  fin = dpp_add<0x140>(fin);
  fin += __shfl_xor(fin, 16);
  fin += __shfl_xor(fin, 32);
  __syncthreads();
  if (lane == 0) fsum[w] = fin;
  __syncthreads();
  if (tid == 0) {
    const float tot = (fsum[0] + fsum[1]) + (fsum[2] + fsum[3]);
    ws[64 + b] = m0 + (float)k_run * 0.6931471805599453f + __logf(tot);
  }
}

// ---------------- final: mean_b(score - logZ) ----------------
__global__ void crf_final(const float* __restrict__ ws, float* __restrict__ out) {
  const int t = threadIdx.x;  // 64
  float v = ws[t] - ws[64 + t];
#pragma unroll
  for (int off = 1; off <= 32; off <<= 1) v += __shfl_xor(v, off);
  if (t == 0) out[0] = v * (1.0f / 64.0f);
}

extern "C" void kernel_launch(void* const* d_in, const int* in_sizes, int n_in,
                              void* d_out, int out_size, void* d_ws, size_t ws_size,
                              hipStream_t stream) {
  const float* em = (const float*)d_in[0];
  const int* tags = (const int*)d_in[1];
  const int* mask = (const int*)d_in[2];
  const float* trans = (const float*)d_in[3];
  const float* startt = (const float*)d_in[4];
  const float* endt = (const float*)d_in[5];
  float* out = (float*)d_out;
  float* ws = (float*)d_ws;

  crf_score<<<B_, 256, 0, stream>>>(em, tags, mask, trans, startt, endt, ws);
  crf_forward<<<B_, 256, 0, stream>>>(em, trans, startt, endt, ws);
  crf_final<<<1, 64, 0, stream>>>(ws, out);
}